// Round 9
// baseline (3179.444 us; speedup 1.0000x reference)
//
#include <hip/hip_runtime.h>
#include <hip/hip_bf16.h>
#include <stdint.h>

#define BATCH 64
#define SEQ   256
#define KDIM  1024
#define NDIM  4096
#define NCAT  16

#define BM 128
#define BN 128
#define BK 64
#define MT (SEQ/BM)              // 2
#define NT (NDIM/BN)             // 32
#define TILES_PER_BATCH (MT*NT)  // 64
#define GEMM_ITEMS (BATCH*TILES_PER_BATCH)  // 4096
#define CVT_X_ITEMS 8192
#define CVT_W_ITEMS (NCAT*1024)             // 16384
#define TOTAL_ITEMS (CVT_X_ITEMS + CVT_W_ITEMS + GEMM_ITEMS)  // 28672

#define WT_BYTES  ((size_t)NCAT * NDIM * KDIM * 2)   // 128 MB
#define XB_BYTES  ((size_t)BATCH * SEQ * KDIM * 2)   // 32 MB
#define CTL_OFF   (WT_BYTES + XB_BYTES)

typedef __attribute__((ext_vector_type(4))) float f32x4;
typedef __attribute__((ext_vector_type(4))) unsigned int u32x4;
typedef __attribute__((ext_vector_type(8))) short bf16x8;

__device__ __forceinline__ unsigned short f2bf(float f) {
  __hip_bfloat16 h = __float2bfloat16(f);
  return __builtin_bit_cast(unsigned short, h);
}
__device__ __forceinline__ unsigned pack2(float lo, float hi) {
  return (unsigned)f2bf(lo) | ((unsigned)f2bf(hi) << 16);
}
__device__ __forceinline__ void gload16(const void* g, void* l) {
  __builtin_amdgcn_global_load_lds(
      (const __attribute__((address_space(1))) unsigned int*)g,
      (__attribute__((address_space(3))) unsigned int*)l, 16, 0, 0);
}

// Layouts (rule 21: linear gload_lds dest + inverse-swizzled source + swizzled
// read). Element (row r, k) of a 128x64 half-tile at byte r*128 + ((k*2)^((r&7)<<4)).
// xb_t: [b][kt][h][16KB]  (h = seq-half)   Wt: [cat][nt256][kt][h][16KB]

__global__ void zero_ctl(int* ctl) {
  if (threadIdx.x < 32) ctl[threadIdx.x] = 0;
}

// work order: [8192 x-cvt] then per cat c: [1024 W-cvt] [cc(c)*64 gemm tiles]
// producer: syncthreads -> threadfence (wbl2) -> device atomicAdd flag
// consumer: relaxed agent polls -> acquire load (inv) -> gload_lds reads
__global__ __launch_bounds__(256, 4)
void mega(const float* __restrict__ x, const float* __restrict__ W,
          const int* __restrict__ cat_ids, const float* __restrict__ bias,
          float* __restrict__ out, unsigned char* __restrict__ xb_t,
          unsigned char* __restrict__ Wt, int* __restrict__ ctl)
{
  __shared__ __align__(16) unsigned char smem[33024];  // 32KB gemm / 16.6KB cvt
  __shared__ int s_wi;
  int* s_cat = (int*)(smem + 32768);

  const int tid  = threadIdx.x;
  const int lane = tid & 63;

  if (tid == 0) s_wi = atomicAdd(&ctl[0], 1);
  __syncthreads();
  const int wi = s_wi;

  // ================= x convert item =================
  if (wi < CVT_X_ITEMS) {
    int g = wi * 256 + tid;
    const int row = g >> 7, c0 = g & 127;
    const int b = row >> 8, s = row & 255;
    const int kt = c0 >> 3, ck = c0 & 7;
    const int h = s >> 7, r = s & 127;
    const float* src = x + (size_t)row * KDIM + c0 * 8;
    f32x4 a = *(const f32x4*)src;
    f32x4 d = *(const f32x4*)(src + 4);
    u32x4 q;
    q[0] = pack2(a[0], a[1]); q[1] = pack2(a[2], a[3]);
    q[2] = pack2(d[0], d[1]); q[3] = pack2(d[2], d[3]);
    unsigned off = (unsigned)(((b * 16 + kt) * 2 + h) * 16384)
                 + (unsigned)(r * 128) + (((unsigned)(ck * 16)) ^ (((unsigned)r & 7u) << 4));
    *(u32x4*)(xb_t + off) = q;
    __syncthreads();
    if (tid == 0) { __threadfence(); atomicAdd(&ctl[1], 1); }
    return;
  }

  // cat table + ballot scan (identical in every wave)
  if (tid < BATCH) s_cat[tid] = cat_ids[tid];
  __syncthreads();
  const int myc = s_cat[lane];

  int wi2 = wi - CVT_X_ITEMS;
  int c = 0, cc = 0;
  unsigned long long mask = 0ULL;
  for (c = 0; c < NCAT; ++c) {
    mask = __ballot(myc == c);
    cc = __popcll(mask);
    int span = 1024 + cc * TILES_PER_BATCH;
    if (wi2 < span) break;
    wi2 -= span;
  }
  if (c >= NCAT) return;
  const int cat = c;

  // ================= W convert item =================
  if (wi2 < 1024) {
    float (*ls)[65] = (float(*)[65])smem;
    const int kt = wi2 >> 6, ntl = wi2 & 63;
    const float* src = W + (size_t)cat * KDIM * NDIM + (size_t)(kt * 64) * NDIM + ntl * 64;
    const int kl = tid >> 4, nl = (tid & 15) * 4;
#pragma unroll
    for (int i = 0; i < 4; ++i) {
      f32x4 v = *(const f32x4*)(src + (size_t)(kl + i * 16) * NDIM + nl);
      ls[kl + i * 16][nl + 0] = v[0];
      ls[kl + i * 16][nl + 1] = v[1];
      ls[kl + i * 16][nl + 2] = v[2];
      ls[kl + i * 16][nl + 3] = v[3];
    }
    __syncthreads();
    const int n = tid >> 2, k2 = (tid & 3) * 16;
    u32x4 q0, q1;
#pragma unroll
    for (int j = 0; j < 4; ++j) q0[j] = pack2(ls[k2 + 2 * j][n],     ls[k2 + 2 * j + 1][n]);
#pragma unroll
    for (int j = 0; j < 4; ++j) q1[j] = pack2(ls[k2 + 8 + 2 * j][n], ls[k2 + 9 + 2 * j][n]);
    const int nt = ntl >> 2, sub = ntl & 3;
    const int h = sub >> 1, rr = (sub & 1) * 64 + n;
    const unsigned sw = ((unsigned)rr & 7u) << 4;
    unsigned base = (unsigned)(cat * 8388608) + (unsigned)(nt * 524288)
                  + (unsigned)((kt * 2 + h) * 16384) + (unsigned)(rr * 128);
    *(u32x4*)(Wt + base + (((unsigned)(k2 * 2))      ^ sw)) = q0;
    *(u32x4*)(Wt + base + (((unsigned)(k2 * 2 + 16)) ^ sw)) = q1;
    __syncthreads();
    if (tid == 0) { __threadfence(); atomicAdd(&ctl[2 + cat], 1); }
    return;
  }

  // ================= GEMM tile =================
  const int idx    = wi2 - 1024;          // [0, cc*64)
  const int per_nt = cc * MT;
  const int nt     = idx / per_nt;
  const int r      = idx % per_nt;
  const int want   = r >> 1;
  const int mt     = r & 1;
  unsigned long long mm = mask;
  for (int i = 0; i < want; ++i) mm &= (mm - 1);
  const int batch = __ffsll((long long)mm) - 1;

  // wait for deps: all of x, and this cat's 1024 W items
  if (tid == 0) {
    int guard = 0;
    while (__hip_atomic_load(&ctl[1], __ATOMIC_RELAXED, __HIP_MEMORY_SCOPE_AGENT) < CVT_X_ITEMS
           && ++guard < (1 << 22)) __builtin_amdgcn_s_sleep(8);
    guard = 0;
    while (__hip_atomic_load(&ctl[2 + cat], __ATOMIC_RELAXED, __HIP_MEMORY_SCOPE_AGENT) < 1024
           && ++guard < (1 << 22)) __builtin_amdgcn_s_sleep(8);
  }
  __syncthreads();
  (void)__hip_atomic_load(&ctl[1], __ATOMIC_ACQUIRE, __HIP_MEMORY_SCOPE_AGENT);  // inv L1/L2

  unsigned char* sA = smem;
  unsigned char* sB = smem + 16384;
  const int m0 = mt * BM;
  const int n0 = nt * BN;
  const unsigned char* Ab = xb_t + (size_t)batch * 524288 + (unsigned)(mt * 16384);
  const unsigned char* Bb = Wt + (size_t)cat * 8388608 + (size_t)(nt >> 1) * 524288
                          + (unsigned)((nt & 1) * 16384);
  const unsigned tb16 = (unsigned)(tid * 16);

  const int lc        = lane & 15;
  const unsigned sw   = ((unsigned)lc & 7u) << 4;
  const unsigned kq16 = (unsigned)((lane >> 4) * 16);
  const unsigned koff0 = kq16 ^ sw;
  const unsigned koff1 = (64u + kq16) ^ sw;

  const int wid = tid >> 6;
  f32x4 acc[4][4] = {};
  const int wr = (wid >> 1) * 64;
  const int wc = (wid & 1) * 64;
  const unsigned rowA = (unsigned)((wr + lc) * 128);
  const unsigned rowB = (unsigned)((wc + lc) * 128);

  for (int kt = 0; kt < KDIM / BK; ++kt) {
    const unsigned ko = (unsigned)(kt * 32768);
    __syncthreads();
#pragma unroll
    for (int s = 0; s < 4; ++s)
      gload16(Ab + ko + (unsigned)(s * 4096) + tb16, sA + s * 4096 + tb16);
#pragma unroll
    for (int s = 0; s < 4; ++s)
      gload16(Bb + ko + (unsigned)(s * 4096) + tb16, sB + s * 4096 + tb16);
    __syncthreads();
#pragma unroll
    for (int kk = 0; kk < 2; ++kk) {
      const unsigned koff = kk ? koff1 : koff0;
      bf16x8 af[4], bfr[4];
#pragma unroll
      for (int mi = 0; mi < 4; ++mi)
        af[mi] = *(const bf16x8*)(sA + rowA + (unsigned)(mi * 2048) + koff);
#pragma unroll
      for (int ni = 0; ni < 4; ++ni)
        bfr[ni] = *(const bf16x8*)(sB + rowB + (unsigned)(ni * 2048) + koff);
#pragma unroll
      for (int mi = 0; mi < 4; ++mi)
#pragma unroll
        for (int ni = 0; ni < 4; ++ni)
          acc[mi][ni] = __builtin_amdgcn_mfma_f32_16x16x32_bf16(af[mi], bfr[ni], acc[mi][ni], 0, 0, 0);
    }
  }

  const int col_l = lane & 15;
  const int row_l = (lane >> 4) * 4;
  float bv4[4];
#pragma unroll
  for (int ni = 0; ni < 4; ++ni)
    bv4[ni] = bias[(size_t)cat * NDIM + (n0 + wc + ni * 16 + col_l)];
#pragma unroll
  for (int mi = 0; mi < 4; ++mi) {
#pragma unroll
    for (int ni = 0; ni < 4; ++ni) {
      int gr = m0 + wr + mi * 16 + row_l;
      int gc = n0 + wc + ni * 16 + col_l;
      f32x4 v = acc[mi][ni];
      size_t o = ((size_t)batch * SEQ + gr) * NDIM + gc;
      out[o]            = v[0] + bv4[ni];
      out[o + NDIM]     = v[1] + bv4[ni];
      out[o + 2 * NDIM] = v[2] + bv4[ni];
      out[o + 3 * NDIM] = v[3] + bv4[ni];
    }
  }
}

// ---------------- fallback: verified R1 kernel (used only if ws too small) ----------------
typedef __attribute__((ext_vector_type(2))) unsigned int u32x2;

__global__ __launch_bounds__(256, 2)
void csl_fallback(const float* __restrict__ x,
                  const int*   __restrict__ cat_ids,
                  const float* __restrict__ W,
                  const float* __restrict__ bias,
                  float* __restrict__ out)
{
  __shared__ __align__(16) unsigned char sA[BM * BK * 2];
  __shared__ __align__(16) unsigned char sB[BN * BK * 2];
  __shared__ int s_cat[BATCH];

  const int tid  = threadIdx.x;
  const int lane = tid & 63;
  const int wid  = tid >> 6;

  if (tid < BATCH) s_cat[tid] = cat_ids[tid];
  __syncthreads();

  const int myc = s_cat[lane];
  int t_id = (int)blockIdx.x;
  int c = 0, base = 0, cc = 0;
  unsigned long long mask = 0ULL;
  for (c = 0; c < NCAT; ++c) {
    mask = __ballot(myc == c);
    cc = __popcll(mask);
    int sz = cc * TILES_PER_BATCH;
    if (t_id < base + sz) break;
    base += sz;
  }
  if (c >= NCAT) return;
  const int idx    = t_id - base;
  const int per_nt = cc * MT;
  const int nt     = idx / per_nt;
  const int r      = idx % per_nt;
  const int want   = r >> 1;
  const int mt     = r & 1;
  unsigned long long mm = mask;
  for (int i = 0; i < want; ++i) mm &= (mm - 1);
  const int batch = __ffsll((long long)mm) - 1;
  const int cat   = c;

  const int m0 = mt * BM;
  const int n0 = nt * BN;

  const size_t x_base = ((size_t)batch * SEQ + m0) * KDIM;
  const size_t w_base = (size_t)cat * KDIM * NDIM + n0;

  f32x4 acc[4][4] = {};
  const int wr = (wid >> 1) * 64;
  const int wc = (wid & 1) * 64;

  for (int kt = 0; kt < KDIM / BK; ++kt) {
    const int k0 = kt * BK;
    f32x4 av[4][2];
#pragma unroll
    for (int s = 0; s < 4; ++s) {
      int seg  = tid + s * 256;
      int arow = seg >> 3;
      int ak   = (seg & 7) << 3;
      const float* gp = x + x_base + (size_t)arow * KDIM + (size_t)(k0 + ak);
      av[s][0] = *(const f32x4*)gp;
      av[s][1] = *(const f32x4*)(gp + 4);
    }
    f32x4 bv[2][4];
#pragma unroll
    for (int s = 0; s < 2; ++s) {
      int u  = tid + s * 256;
      int nq = u & 31;
      int kq = u >> 5;
      const float* gp = W + w_base + (size_t)(k0 + kq * 4) * NDIM + (size_t)(nq * 4);
#pragma unroll
      for (int rr = 0; rr < 4; ++rr)
        bv[s][rr] = *(const f32x4*)(gp + (size_t)rr * NDIM);
    }
    __syncthreads();
#pragma unroll
    for (int s = 0; s < 4; ++s) {
      int seg  = tid + s * 256;
      int arow = seg >> 3;
      int akb  = (seg & 7) << 4;
      unsigned byte = (unsigned)(arow * (BK * 2)) + ((unsigned)akb ^ (((unsigned)arow & 7u) << 4));
      u32x4 q;
      q[0] = pack2(av[s][0][0], av[s][0][1]);
      q[1] = pack2(av[s][0][2], av[s][0][3]);
      q[2] = pack2(av[s][1][0], av[s][1][1]);
      q[3] = pack2(av[s][1][2], av[s][1][3]);
      *(u32x4*)(sA + byte) = q;
    }
#pragma unroll
    for (int s = 0; s < 2; ++s) {
      int u  = tid + s * 256;
      int nq = u & 31;
      int kq = u >> 5;
      unsigned swz = ((unsigned)nq & 7u) << 4;
#pragma unroll
      for (int i = 0; i < 4; ++i) {
        int n = nq * 4 + i;
        unsigned byte = (unsigned)(n * (BK * 2)) + (((unsigned)(kq * 8)) ^ swz);
        u32x2 d;
        d[0] = pack2(bv[s][0][i], bv[s][1][i]);
        d[1] = pack2(bv[s][2][i], bv[s][3][i]);
        *(u32x2*)(sB + byte) = d;
      }
    }
    __syncthreads();
#pragma unroll
    for (int kk = 0; kk < 2; ++kk) {
      const int kb = kk * 64 + ((lane >> 4) << 4);
      bf16x8 af[4], bfr[4];
#pragma unroll
      for (int mi = 0; mi < 4; ++mi) {
        int row = wr + mi * 16 + (lane & 15);
        unsigned byte = (unsigned)(row * (BK * 2)) + ((unsigned)kb ^ (((unsigned)row & 7u) << 4));
        af[mi] = *(const bf16x8*)(sA + byte);
      }
#pragma unroll
      for (int ni = 0; ni < 4; ++ni) {
        int n = wc + ni * 16 + (lane & 15);
        unsigned byte = (unsigned)(n * (BK * 2)) + ((unsigned)kb ^ ((((unsigned)n >> 2) & 7u) << 4));
        bfr[ni] = *(const bf16x8*)(sB + byte);
      }
#pragma unroll
      for (int mi = 0; mi < 4; ++mi)
#pragma unroll
        for (int ni = 0; ni < 4; ++ni)
          acc[mi][ni] = __builtin_amdgcn_mfma_f32_16x16x32_bf16(af[mi], bfr[ni], acc[mi][ni], 0, 0, 0);
    }
  }

  const int col_l = lane & 15;
  const int row_l = (lane >> 4) * 4;
#pragma unroll
  for (int mi = 0; mi < 4; ++mi) {
#pragma unroll
    for (int ni = 0; ni < 4; ++ni) {
      int gr = m0 + wr + mi * 16 + row_l;
      int gc = n0 + wc + ni * 16 + col_l;
      float bvl = bias[(size_t)cat * NDIM + gc];
      f32x4 v = acc[mi][ni];
      size_t o = ((size_t)batch * SEQ + gr) * NDIM + gc;
      out[o]            = v[0] + bvl;
      out[o + NDIM]     = v[1] + bvl;
      out[o + 2 * NDIM] = v[2] + bvl;
      out[o + 3 * NDIM] = v[3] + bvl;
    }
  }
}

extern "C" void kernel_launch(void* const* d_in, const int* in_sizes, int n_in,
                              void* d_out, int out_size, void* d_ws, size_t ws_size,
                              hipStream_t stream) {
  const float* x       = (const float*)d_in[0];
  const int*   cat_ids = (const int*)d_in[1];
  const float* W       = (const float*)d_in[2];
  const float* bias    = (const float*)d_in[3];
  float*       out     = (float*)d_out;
  (void)in_sizes; (void)n_in; (void)out_size;

  const size_t need = CTL_OFF + 4096;

  if (ws_size >= need) {
    unsigned char* Wt   = (unsigned char*)d_ws;
    unsigned char* xb_t = Wt + WT_BYTES;
    int*           ctl  = (int*)((unsigned char*)d_ws + CTL_OFF);
    hipLaunchKernelGGL(zero_ctl, dim3(1), dim3(64), 0, stream, ctl);
    hipLaunchKernelGGL(mega, dim3(TOTAL_ITEMS), dim3(256), 0, stream,
                       x, W, cat_ids, bias, out, xb_t, Wt, ctl);
  } else {
    hipLaunchKernelGGL(csl_fallback, dim3(BATCH * TILES_PER_BATCH), dim3(256), 0, stream,
                       x, cat_ids, W, bias, out);
  }
}

// Round 10
// 280.748 us; speedup vs baseline: 11.3249x; 11.3249x over previous
//
#include <hip/hip_runtime.h>
#include <hip/hip_bf16.h>
#include <stdint.h>

#define BATCH 64
#define SEQ   256
#define KDIM  1024
#define NDIM  4096
#define NCAT  16

// ---- GEMM geometry: 128x128 tile, BK=64, 4 waves, 256 threads ----
#define BM 128
#define BN 128
#define BK 64
#define MT (SEQ/BM)              // 2
#define NT (NDIM/BN)             // 32
#define TILES_PER_BATCH (MT*NT)  // 64
#define NBLOCKS (BATCH*TILES_PER_BATCH)  // 4096

typedef __attribute__((ext_vector_type(4))) float f32x4;
typedef __attribute__((ext_vector_type(4))) unsigned int u32x4;
typedef __attribute__((ext_vector_type(8))) short bf16x8;

__device__ __forceinline__ unsigned short f2bf(float f) {
  __hip_bfloat16 h = __float2bfloat16(f);
  return __builtin_bit_cast(unsigned short, h);
}
__device__ __forceinline__ unsigned pack2(float lo, float hi) {
  return (unsigned)f2bf(lo) | ((unsigned)f2bf(hi) << 16);
}
__device__ __forceinline__ void gload16(const void* g, void* l) {
  __builtin_amdgcn_global_load_lds(
      (const __attribute__((address_space(1))) unsigned int*)g,
      (__attribute__((address_space(3))) unsigned int*)l, 16, 0, 0);
}

// Tiled+pre-swizzled layouts (rule 21: linear gload_lds dest + inverse-swizzled
// source + swizzled read). Element (row r, k) of a 128-row x 64-k half-tile
// lives at byte: r*128 + ((k*2) ^ ((r&7)<<4)), inside a 16 KiB block.
// xb_t: [b][kt][h][16KB]  (h = seq-half)   Wt: [cat][nt256][kt][h][16KB]  (h = col-half)
// A 128^2 GEMM tile consumes exactly ONE 16 KiB block per operand per K-step.

// ---------------- pass 1 (fused): x and W fp32 -> tiled swizzled bf16 ----------------
#define CVT_W_BLOCKS (NCAT*(KDIM/64)*(NDIM/64))          // 16384
#define CVT_X_BLOCKS ((BATCH*SEQ*KDIM/8)/256)            // 8192

__global__ void cvt_fused(const float* __restrict__ x,
                          const float* __restrict__ W,
                          unsigned char* __restrict__ xb_t,
                          unsigned char* __restrict__ Wt) {
  __shared__ float ls[64][65];
  const int tid = threadIdx.x;

  if (blockIdx.x < CVT_W_BLOCKS) {
    // ---- W: [cat][k][n] -> [cat][nt256][kt][h][16KB swizzled] ----
    const int bid = blockIdx.x;
    const int cat = bid >> 10;
    const int rem = bid & 1023;
    const int kt  = rem >> 6;                   // k-tile of 64
    const int ntl = rem & 63;                   // n-tile of 64

    const float* src = W + (size_t)cat * KDIM * NDIM + (size_t)(kt * 64) * NDIM + ntl * 64;
    const int kl = tid >> 4;
    const int nl = (tid & 15) * 4;
#pragma unroll
    for (int i = 0; i < 4; ++i) {
      f32x4 v = *(const f32x4*)(src + (size_t)(kl + i * 16) * NDIM + nl);
      ls[kl + i * 16][nl + 0] = v[0];
      ls[kl + i * 16][nl + 1] = v[1];
      ls[kl + i * 16][nl + 2] = v[2];
      ls[kl + i * 16][nl + 3] = v[3];
    }
    __syncthreads();
    const int n  = tid >> 2;                    // 0..63
    const int k2 = (tid & 3) * 16;              // elem chunk base
    u32x4 q0, q1;
#pragma unroll
    for (int j = 0; j < 4; ++j) q0[j] = pack2(ls[k2 + 2 * j][n],     ls[k2 + 2 * j + 1][n]);
#pragma unroll
    for (int j = 0; j < 4; ++j) q1[j] = pack2(ls[k2 + 8 + 2 * j][n], ls[k2 + 9 + 2 * j][n]);

    const int nt   = ntl >> 2;
    const int sub  = ntl & 3;
    const int h    = sub >> 1;
    const int r    = (sub & 1) * 64 + n;
    const unsigned sw = ((unsigned)r & 7u) << 4;
    unsigned base = (unsigned)(cat * 8388608) + (unsigned)(nt * 524288)
                  + (unsigned)((kt * 2 + h) * 16384) + (unsigned)(r * 128);
    *(u32x4*)(Wt + base + (((unsigned)(k2 * 2))      ^ sw)) = q0;
    *(u32x4*)(Wt + base + (((unsigned)(k2 * 2 + 16)) ^ sw)) = q1;
  } else {
    // ---- x: [b][s][k] -> [b][kt][h][16KB swizzled] ----
    int g = (blockIdx.x - CVT_W_BLOCKS) * 256 + tid;   // one 16B chunk (8 k-elems)
    const int row = g >> 7;                     // b*256 + s
    const int c   = g & 127;                    // k-chunk index
    const int b   = row >> 8;
    const int s   = row & 255;
    const int kt  = c >> 3;
    const int ck  = c & 7;
    const int h   = s >> 7;
    const int r   = s & 127;
    const float* src = x + (size_t)row * KDIM + c * 8;
    f32x4 a = *(const f32x4*)src;
    f32x4 d = *(const f32x4*)(src + 4);
    u32x4 q;
    q[0] = pack2(a[0], a[1]); q[1] = pack2(a[2], a[3]);
    q[2] = pack2(d[0], d[1]); q[3] = pack2(d[2], d[3]);
    unsigned off = (unsigned)(((b * 16 + kt) * 2 + h) * 16384)
                 + (unsigned)(r * 128) + (((unsigned)(ck * 16)) ^ (((unsigned)r & 7u) << 4));
    *(u32x4*)(xb_t + off) = q;
  }
}

// ---------------- pass 2: 128^2 2-barrier GEMM, swizzled LDS ----------------
__global__ __launch_bounds__(256, 4)
void csl_gemm(const unsigned char* __restrict__ xb_t,
              const unsigned char* __restrict__ Wt,
              const int*   __restrict__ cat_ids,
              const float* __restrict__ bias,
              float* __restrict__ out)
{
  __shared__ __align__(16) unsigned char sA[BM * BK * 2];  // 16 KB, swizzled layout
  __shared__ __align__(16) unsigned char sB[BN * BK * 2];  // 16 KB
  __shared__ int s_cat[BATCH];

  const int tid  = threadIdx.x;
  const int lane = tid & 63;
  const int wid  = tid >> 6;

  if (tid < BATCH) s_cat[tid] = cat_ids[tid];
  __syncthreads();

  // T1: bijective XCD swizzle (4096 % 8 == 0), forward order (R7 reversal was -3%)
  const int bid  = (int)blockIdx.x;
  const int t_id = (bid & 7) * (NBLOCKS / 8) + (bid >> 3);

  // category-sorted decode: tiles ordered (cat, n-tile, batch, m-tile)
  const int myc = s_cat[lane];
  int c = 0, base = 0, cc = 0;
  unsigned long long mask = 0ULL;
  for (c = 0; c < NCAT; ++c) {
    mask = __ballot(myc == c);
    cc = __popcll(mask);
    int sz = cc * TILES_PER_BATCH;
    if (t_id < base + sz) break;
    base += sz;
  }
  if (c >= NCAT) return;
  const int idx    = t_id - base;
  const int per_nt = cc * MT;
  const int nt     = idx / per_nt;     // 128-col tile, 0..31
  const int r      = idx % per_nt;
  const int want   = r >> 1;
  const int mt     = r & 1;
  unsigned long long mm = mask;
  for (int i = 0; i < want; ++i) mm &= (mm - 1);
  const int batch = __ffsll((long long)mm) - 1;
  const int cat   = c;

  const int m0 = mt * BM;
  const int n0 = nt * BN;

  // 16 KB block bases: A = [b][kt][h=mt]; B = [cat][nt>>1][kt][h=nt&1]
  const unsigned char* Ab = xb_t + (size_t)batch * 524288 + (unsigned)(mt * 16384);
  const unsigned char* Bb = Wt + (size_t)cat * 8388608 + (size_t)(nt >> 1) * 524288
                          + (unsigned)((nt & 1) * 16384);

  const unsigned tb16 = (unsigned)(tid * 16);

  // fragment read addressing (XOR swizzle; row&7 == lc&7 since rows step by 16)
  const int lc        = lane & 15;
  const unsigned sw   = ((unsigned)lc & 7u) << 4;
  const unsigned kq16 = (unsigned)((lane >> 4) * 16);
  const unsigned koff0 = kq16 ^ sw;
  const unsigned koff1 = (64u + kq16) ^ sw;

  f32x4 acc[4][4] = {};
  const int wr = (wid >> 1) * 64;
  const int wc = (wid & 1) * 64;
  const unsigned rowA = (unsigned)((wr + lc) * 128);
  const unsigned rowB = (unsigned)((wc + lc) * 128);

  for (int kt = 0; kt < KDIM / BK; ++kt) {
    const unsigned ko = (unsigned)(kt * 32768);
    __syncthreads();                  // previous compute done reading LDS
#pragma unroll
    for (int s = 0; s < 4; ++s)
      gload16(Ab + ko + (unsigned)(s * 4096) + tb16, sA + s * 4096 + tb16);
#pragma unroll
    for (int s = 0; s < 4; ++s)
      gload16(Bb + ko + (unsigned)(s * 4096) + tb16, sB + s * 4096 + tb16);
    __syncthreads();                  // drains vmcnt: tiles staged
#pragma unroll
    for (int kk = 0; kk < 2; ++kk) {
      const unsigned koff = kk ? koff1 : koff0;
      bf16x8 af[4], bfr[4];
#pragma unroll
      for (int mi = 0; mi < 4; ++mi)
        af[mi] = *(const bf16x8*)(sA + rowA + (unsigned)(mi * 2048) + koff);
#pragma unroll
      for (int ni = 0; ni < 4; ++ni)
        bfr[ni] = *(const bf16x8*)(sB + rowB + (unsigned)(ni * 2048) + koff);
#pragma unroll
      for (int mi = 0; mi < 4; ++mi)
#pragma unroll
        for (int ni = 0; ni < 4; ++ni)
          acc[mi][ni] = __builtin_amdgcn_mfma_f32_16x16x32_bf16(af[mi], bfr[ni], acc[mi][ni], 0, 0, 0);
    }
  }

  // epilogue: bias (hoisted: 4 distinct values per thread) + fp32 store
  const int col_l = lane & 15;
  const int row_l = (lane >> 4) * 4;
  float bv4[4];
#pragma unroll
  for (int ni = 0; ni < 4; ++ni)
    bv4[ni] = bias[(size_t)cat * NDIM + (n0 + wc + ni * 16 + col_l)];
#pragma unroll
  for (int mi = 0; mi < 4; ++mi) {
#pragma unroll
    for (int ni = 0; ni < 4; ++ni) {
      int gr = m0 + wr + mi * 16 + row_l;
      int gc = n0 + wc + ni * 16 + col_l;
      f32x4 v = acc[mi][ni];
      size_t o = ((size_t)batch * SEQ + gr) * NDIM + gc;
      out[o]            = v[0] + bv4[ni];
      out[o + NDIM]     = v[1] + bv4[ni];
      out[o + 2 * NDIM] = v[2] + bv4[ni];
      out[o + 3 * NDIM] = v[3] + bv4[ni];
    }
  }
}

// ---------------- fallback: verified R1 kernel (used only if ws too small) ----------------
typedef __attribute__((ext_vector_type(2))) unsigned int u32x2;

__global__ __launch_bounds__(256, 2)
void csl_fallback(const float* __restrict__ x,
                  const int*   __restrict__ cat_ids,
                  const float* __restrict__ W,
                  const float* __restrict__ bias,
                  float* __restrict__ out)
{
  __shared__ __align__(16) unsigned char sA[BM * BK * 2];
  __shared__ __align__(16) unsigned char sB[BN * BK * 2];
  __shared__ int s_cat[BATCH];

  const int tid  = threadIdx.x;
  const int lane = tid & 63;
  const int wid  = tid >> 6;

  if (tid < BATCH) s_cat[tid] = cat_ids[tid];
  __syncthreads();

  const int myc = s_cat[lane];
  int t_id = (int)blockIdx.x;
  int c = 0, base = 0, cc = 0;
  unsigned long long mask = 0ULL;
  for (c = 0; c < NCAT; ++c) {
    mask = __ballot(myc == c);
    cc = __popcll(mask);
    int sz = cc * TILES_PER_BATCH;
    if (t_id < base + sz) break;
    base += sz;
  }
  if (c >= NCAT) return;
  const int idx    = t_id - base;
  const int per_nt = cc * MT;
  const int nt     = idx / per_nt;
  const int r      = idx % per_nt;
  const int want   = r >> 1;
  const int mt     = r & 1;
  unsigned long long mm = mask;
  for (int i = 0; i < want; ++i) mm &= (mm - 1);
  const int batch = __ffsll((long long)mm) - 1;
  const int cat   = c;

  const int m0 = mt * BM;
  const int n0 = nt * BN;

  const size_t x_base = ((size_t)batch * SEQ + m0) * KDIM;
  const size_t w_base = (size_t)cat * KDIM * NDIM + n0;

  f32x4 acc[4][4] = {};
  const int wr = (wid >> 1) * 64;
  const int wc = (wid & 1) * 64;

  for (int kt = 0; kt < KDIM / BK; ++kt) {
    const int k0 = kt * BK;
    f32x4 av[4][2];
#pragma unroll
    for (int s = 0; s < 4; ++s) {
      int seg  = tid + s * 256;
      int arow = seg >> 3;
      int ak   = (seg & 7) << 3;
      const float* gp = x + x_base + (size_t)arow * KDIM + (size_t)(k0 + ak);
      av[s][0] = *(const f32x4*)gp;
      av[s][1] = *(const f32x4*)(gp + 4);
    }
    f32x4 bv[2][4];
#pragma unroll
    for (int s = 0; s < 2; ++s) {
      int u  = tid + s * 256;
      int nq = u & 31;
      int kq = u >> 5;
      const float* gp = W + w_base + (size_t)(k0 + kq * 4) * NDIM + (size_t)(nq * 4);
#pragma unroll
      for (int rr = 0; rr < 4; ++rr)
        bv[s][rr] = *(const f32x4*)(gp + (size_t)rr * NDIM);
    }
    __syncthreads();
#pragma unroll
    for (int s = 0; s < 4; ++s) {
      int seg  = tid + s * 256;
      int arow = seg >> 3;
      int akb  = (seg & 7) << 4;
      unsigned byte = (unsigned)(arow * (BK * 2)) + ((unsigned)akb ^ (((unsigned)arow & 7u) << 4));
      u32x4 q;
      q[0] = pack2(av[s][0][0], av[s][0][1]);
      q[1] = pack2(av[s][0][2], av[s][0][3]);
      q[2] = pack2(av[s][1][0], av[s][1][1]);
      q[3] = pack2(av[s][1][2], av[s][1][3]);
      *(u32x4*)(sA + byte) = q;
    }
#pragma unroll
    for (int s = 0; s < 2; ++s) {
      int u  = tid + s * 256;
      int nq = u & 31;
      int kq = u >> 5;
      unsigned swz = ((unsigned)nq & 7u) << 4;
#pragma unroll
      for (int i = 0; i < 4; ++i) {
        int n = nq * 4 + i;
        unsigned byte = (unsigned)(n * (BK * 2)) + (((unsigned)(kq * 8)) ^ swz);
        u32x2 d;
        d[0] = pack2(bv[s][0][i], bv[s][1][i]);
        d[1] = pack2(bv[s][2][i], bv[s][3][i]);
        *(u32x2*)(sB + byte) = d;
      }
    }
    __syncthreads();
#pragma unroll
    for (int kk = 0; kk < 2; ++kk) {
      const int kb = kk * 64 + ((lane >> 4) << 4);
      bf16x8 af[4], bfr[4];
#pragma unroll
      for (int mi = 0; mi < 4; ++mi) {
        int row = wr + mi * 16 + (lane & 15);
        unsigned byte = (unsigned)(row * (BK * 2)) + ((unsigned)kb ^ (((unsigned)row & 7u) << 4));
        af[mi] = *(const bf16x8*)(sA + byte);
      }
#pragma unroll
      for (int ni = 0; ni < 4; ++ni) {
        int n = wc + ni * 16 + (lane & 15);
        unsigned byte = (unsigned)(n * (BK * 2)) + ((unsigned)kb ^ ((((unsigned)n >> 2) & 7u) << 4));
        bfr[ni] = *(const bf16x8*)(sB + byte);
      }
#pragma unroll
      for (int mi = 0; mi < 4; ++mi)
#pragma unroll
        for (int ni = 0; ni < 4; ++ni)
          acc[mi][ni] = __builtin_amdgcn_mfma_f32_16x16x32_bf16(af[mi], bfr[ni], acc[mi][ni], 0, 0, 0);
    }
  }

  const int col_l = lane & 15;
  const int row_l = (lane >> 4) * 4;
#pragma unroll
  for (int mi = 0; mi < 4; ++mi) {
#pragma unroll
    for (int ni = 0; ni < 4; ++ni) {
      int gr = m0 + wr + mi * 16 + row_l;
      int gc = n0 + wc + ni * 16 + col_l;
      float bvl = bias[(size_t)cat * NDIM + gc];
      f32x4 v = acc[mi][ni];
      size_t o = ((size_t)batch * SEQ + gr) * NDIM + gc;
      out[o]            = v[0] + bvl;
      out[o + NDIM]     = v[1] + bvl;
      out[o + 2 * NDIM] = v[2] + bvl;
      out[o + 3 * NDIM] = v[3] + bvl;
    }
  }
}

extern "C" void kernel_launch(void* const* d_in, const int* in_sizes, int n_in,
                              void* d_out, int out_size, void* d_ws, size_t ws_size,
                              hipStream_t stream) {
  const float* x       = (const float*)d_in[0];
  const int*   cat_ids = (const int*)d_in[1];
  const float* W       = (const float*)d_in[2];
  const float* bias    = (const float*)d_in[3];
  float*       out     = (float*)d_out;
  (void)in_sizes; (void)n_in; (void)out_size;

  const size_t wt_bytes = (size_t)NCAT * NDIM * KDIM * 2;   // 128 MB tiled bf16 W
  const size_t xb_bytes = (size_t)BATCH * SEQ * KDIM * 2;   // 32 MB tiled bf16 x
  const size_t need = wt_bytes + xb_bytes;

  if (ws_size >= need) {
    unsigned char* Wt   = (unsigned char*)d_ws;
    unsigned char* xb_t = Wt + wt_bytes;
    hipLaunchKernelGGL(cvt_fused, dim3(CVT_W_BLOCKS + CVT_X_BLOCKS), dim3(256), 0, stream,
                       x, W, xb_t, Wt);
    hipLaunchKernelGGL(csl_gemm, dim3(NBLOCKS), dim3(256), 0, stream,
                       xb_t, Wt, cat_ids, bias, out);
  } else {
    hipLaunchKernelGGL(csl_fallback, dim3(NBLOCKS), dim3(256), 0, stream,
                       x, cat_ids, W, bias, out);
  }
}

// Round 11
// 258.749 us; speedup vs baseline: 12.2877x; 1.0850x over previous
//
#include <hip/hip_runtime.h>
#include <hip/hip_bf16.h>
#include <stdint.h>

#define BATCH 64
#define SEQ   256
#define KDIM  1024
#define NDIM  4096
#define NCAT  16

// ---- fallback geometry (128x128) ----
#define BM 128
#define BN 128
#define BK 64
#define MT (SEQ/BM)              // 2
#define NT (NDIM/BN)             // 32
#define TILES_PER_BATCH (MT*NT)  // 64
#define NBLOCKS (BATCH*TILES_PER_BATCH)  // 4096

// ---- main GEMM geometry: 256x128 tile, BK=64, 4 waves (2m x 2n), 256 threads ----
#define GBM 256
#define GBN 128
#define G_NT (NDIM/GBN)              // 32
#define G_NBLOCKS (BATCH*G_NT)       // 2048

typedef __attribute__((ext_vector_type(4))) float f32x4;
typedef __attribute__((ext_vector_type(4))) unsigned int u32x4;
typedef __attribute__((ext_vector_type(8))) short bf16x8;

__device__ __forceinline__ unsigned short f2bf(float f) {
  __hip_bfloat16 h = __float2bfloat16(f);
  return __builtin_bit_cast(unsigned short, h);
}
__device__ __forceinline__ unsigned pack2(float lo, float hi) {
  return (unsigned)f2bf(lo) | ((unsigned)f2bf(hi) << 16);
}
__device__ __forceinline__ void gload16(const void* g, void* l) {
  __builtin_amdgcn_global_load_lds(
      (const __attribute__((address_space(1))) unsigned int*)g,
      (__attribute__((address_space(3))) unsigned int*)l, 16, 0, 0);
}

// Tiled+pre-swizzled layouts (rule 21: linear gload_lds dest + inverse-swizzled
// source + swizzled read). Element (row r, k) of a 128-row x 64-k half-tile
// lives at byte: r*128 + ((k*2) ^ ((r&7)<<4)), inside a 16 KiB block.
// xb_t: [b][kt][h][16KB]  (h = seq-half)   Wt: [cat][nt256][kt][h][16KB]  (h = col-half)
// The 256x128 GEMM tile consumes BOTH A halves (32KB contiguous) + ONE B block.

// ---------------- pass 1 (fused): x and W fp32 -> tiled swizzled bf16 ----------------
#define CVT_W_BLOCKS (NCAT*(KDIM/64)*(NDIM/64))          // 16384
#define CVT_X_BLOCKS ((BATCH*SEQ*KDIM/8)/256)            // 8192

__global__ void cvt_fused(const float* __restrict__ x,
                          const float* __restrict__ W,
                          unsigned char* __restrict__ xb_t,
                          unsigned char* __restrict__ Wt) {
  __shared__ float ls[64][65];
  const int tid = threadIdx.x;

  if (blockIdx.x < CVT_W_BLOCKS) {
    // ---- W: [cat][k][n] -> [cat][nt256][kt][h][16KB swizzled] ----
    const int bid = blockIdx.x;
    const int cat = bid >> 10;
    const int rem = bid & 1023;
    const int kt  = rem >> 6;                   // k-tile of 64
    const int ntl = rem & 63;                   // n-tile of 64

    const float* src = W + (size_t)cat * KDIM * NDIM + (size_t)(kt * 64) * NDIM + ntl * 64;
    const int kl = tid >> 4;
    const int nl = (tid & 15) * 4;
#pragma unroll
    for (int i = 0; i < 4; ++i) {
      f32x4 v = *(const f32x4*)(src + (size_t)(kl + i * 16) * NDIM + nl);
      ls[kl + i * 16][nl + 0] = v[0];
      ls[kl + i * 16][nl + 1] = v[1];
      ls[kl + i * 16][nl + 2] = v[2];
      ls[kl + i * 16][nl + 3] = v[3];
    }
    __syncthreads();
    const int n  = tid >> 2;                    // 0..63
    const int k2 = (tid & 3) * 16;              // elem chunk base
    u32x4 q0, q1;
#pragma unroll
    for (int j = 0; j < 4; ++j) q0[j] = pack2(ls[k2 + 2 * j][n],     ls[k2 + 2 * j + 1][n]);
#pragma unroll
    for (int j = 0; j < 4; ++j) q1[j] = pack2(ls[k2 + 8 + 2 * j][n], ls[k2 + 9 + 2 * j][n]);

    const int nt   = ntl >> 2;
    const int sub  = ntl & 3;
    const int h    = sub >> 1;
    const int r    = (sub & 1) * 64 + n;
    const unsigned sw = ((unsigned)r & 7u) << 4;
    unsigned base = (unsigned)(cat * 8388608) + (unsigned)(nt * 524288)
                  + (unsigned)((kt * 2 + h) * 16384) + (unsigned)(r * 128);
    *(u32x4*)(Wt + base + (((unsigned)(k2 * 2))      ^ sw)) = q0;
    *(u32x4*)(Wt + base + (((unsigned)(k2 * 2 + 16)) ^ sw)) = q1;
  } else {
    // ---- x: [b][s][k] -> [b][kt][h][16KB swizzled] ----
    int g = (blockIdx.x - CVT_W_BLOCKS) * 256 + tid;   // one 16B chunk (8 k-elems)
    const int row = g >> 7;                     // b*256 + s
    const int c   = g & 127;                    // k-chunk index
    const int b   = row >> 8;
    const int s   = row & 255;
    const int kt  = c >> 3;
    const int ck  = c & 7;
    const int h   = s >> 7;
    const int r   = s & 127;
    const float* src = x + (size_t)row * KDIM + c * 8;
    f32x4 a = *(const f32x4*)src;
    f32x4 d = *(const f32x4*)(src + 4);
    u32x4 q;
    q[0] = pack2(a[0], a[1]); q[1] = pack2(a[2], a[3]);
    q[2] = pack2(d[0], d[1]); q[3] = pack2(d[2], d[3]);
    unsigned off = (unsigned)(((b * 16 + kt) * 2 + h) * 16384)
                 + (unsigned)(r * 128) + (((unsigned)(ck * 16)) ^ (((unsigned)r & 7u) << 4));
    *(u32x4*)(xb_t + off) = q;
  }
}

// ---------------- pass 2: 256x128 2-barrier GEMM, swizzled LDS ----------------
// 4 waves (wm in {0,1} x wn in {0,1}), each wave owns a 128x64 output block ->
// 64 MFMA per K-step per wave against ONE stage+drain (2x the 128^2 ratio).
__global__ __launch_bounds__(256, 2)
void csl_gemm(const unsigned char* __restrict__ xb_t,
              const unsigned char* __restrict__ Wt,
              const int*   __restrict__ cat_ids,
              const float* __restrict__ bias,
              float* __restrict__ out)
{
  __shared__ __align__(16) unsigned char sA[GBM * BK * 2];  // 32 KB (both halves)
  __shared__ __align__(16) unsigned char sB[GBN * BK * 2];  // 16 KB
  __shared__ int s_cat[BATCH];

  const int tid  = threadIdx.x;
  const int lane = tid & 63;
  const int wid  = tid >> 6;
  const int wm   = wid >> 1;          // 0..1  (m-half of 128 rows)
  const int wn   = wid & 1;           // 0..1  (n-half of 64 cols)

  if (tid < BATCH) s_cat[tid] = cat_ids[tid];
  __syncthreads();

  // T1: bijective XCD swizzle (2048 % 8 == 0), forward order
  const int bid  = (int)blockIdx.x;
  const int t_id = (bid & 7) * (G_NBLOCKS / 8) + (bid >> 3);

  // category-sorted decode: tiles ordered (cat, n-tile, batch)
  const int myc = s_cat[lane];
  int c = 0, base = 0, cc = 0;
  unsigned long long mask = 0ULL;
  for (c = 0; c < NCAT; ++c) {
    mask = __ballot(myc == c);
    cc = __popcll(mask);
    int sz = cc * G_NT;
    if (t_id < base + sz) break;
    base += sz;
  }
  if (c >= NCAT) return;
  const int idx = t_id - base;
  const int nt  = idx / cc;            // 128-col tile, 0..31
  const int pos = idx % cc;
  unsigned long long mm = mask;
  for (int i = 0; i < pos; ++i) mm &= (mm - 1);
  const int batch = __ffsll((long long)mm) - 1;
  const int cat   = c;

  const int n0 = nt * GBN;

  // A = full xb_t[b][kt] (32KB contiguous); B = [cat][nt>>1][kt][h=nt&1]
  const unsigned char* Ab = xb_t + (size_t)batch * 524288;
  const unsigned char* Bb = Wt + (size_t)cat * 8388608 + (size_t)(nt >> 1) * 524288
                          + (unsigned)((nt & 1) * 16384);

  const unsigned tb16 = (unsigned)(tid * 16);

  // fragment read addressing (XOR swizzle; row&7 == lc&7 since rows step by 16)
  const int lc        = lane & 15;
  const unsigned sw   = ((unsigned)lc & 7u) << 4;
  const unsigned kq16 = (unsigned)((lane >> 4) * 16);
  const unsigned koff0 = kq16 ^ sw;
  const unsigned koff1 = (64u + kq16) ^ sw;

  f32x4 acc[8][4] = {};
  const unsigned rA   = (unsigned)(wm * 16384 + lc * 128);  // h-block wm, row lc
  const unsigned rowB = (unsigned)(wn * 8192 + lc * 128);

  for (int kt = 0; kt < KDIM / BK; ++kt) {
    const unsigned ko = (unsigned)(kt * 32768);
    __syncthreads();                  // previous compute done reading LDS
#pragma unroll
    for (int s = 0; s < 8; ++s)
      gload16(Ab + ko + (unsigned)(s * 4096) + tb16, sA + s * 4096 + tb16);
#pragma unroll
    for (int s = 0; s < 4; ++s)
      gload16(Bb + ko + (unsigned)(s * 4096) + tb16, sB + s * 4096 + tb16);
    __syncthreads();                  // drains vmcnt: tiles staged
#pragma unroll
    for (int kk = 0; kk < 2; ++kk) {
      const unsigned koff = kk ? koff1 : koff0;
      bf16x8 bfr[4];
#pragma unroll
      for (int ni = 0; ni < 4; ++ni)
        bfr[ni] = *(const bf16x8*)(sB + rowB + (unsigned)(ni * 2048) + koff);
#pragma unroll
      for (int mh = 0; mh < 2; ++mh) {
        bf16x8 af[4];
#pragma unroll
        for (int mi = 0; mi < 4; ++mi)
          af[mi] = *(const bf16x8*)(sA + rA + (unsigned)(mh * 8192 + mi * 2048) + koff);
#pragma unroll
        for (int mi = 0; mi < 4; ++mi)
#pragma unroll
          for (int ni = 0; ni < 4; ++ni)
            acc[mh * 4 + mi][ni] = __builtin_amdgcn_mfma_f32_16x16x32_bf16(
                af[mi], bfr[ni], acc[mh * 4 + mi][ni], 0, 0, 0);
      }
    }
  }

  // epilogue: bias (hoisted) + fp32 store
  const int col_l = lane & 15;
  const int row_l = (lane >> 4) * 4;
  float bv4[4];
#pragma unroll
  for (int ni = 0; ni < 4; ++ni)
    bv4[ni] = bias[(size_t)cat * NDIM + (n0 + wn * 64 + ni * 16 + col_l)];
#pragma unroll
  for (int mf = 0; mf < 8; ++mf) {
#pragma unroll
    for (int ni = 0; ni < 4; ++ni) {
      int gr = wm * 128 + (mf >> 2) * 64 + (mf & 3) * 16 + row_l;
      int gc = n0 + wn * 64 + ni * 16 + col_l;
      f32x4 v = acc[mf][ni];
      size_t o = ((size_t)batch * SEQ + gr) * NDIM + gc;
      out[o]            = v[0] + bv4[ni];
      out[o + NDIM]     = v[1] + bv4[ni];
      out[o + 2 * NDIM] = v[2] + bv4[ni];
      out[o + 3 * NDIM] = v[3] + bv4[ni];
    }
  }
}

// ---------------- fallback: verified R1 kernel (used only if ws too small) ----------------
typedef __attribute__((ext_vector_type(2))) unsigned int u32x2;

__global__ __launch_bounds__(256, 2)
void csl_fallback(const float* __restrict__ x,
                  const int*   __restrict__ cat_ids,
                  const float* __restrict__ W,
                  const float* __restrict__ bias,
                  float* __restrict__ out)
{
  __shared__ __align__(16) unsigned char sA[BM * BK * 2];
  __shared__ __align__(16) unsigned char sB[BN * BK * 2];
  __shared__ int s_cat[BATCH];

  const int tid  = threadIdx.x;
  const int lane = tid & 63;
  const int wid  = tid >> 6;

  if (tid < BATCH) s_cat[tid] = cat_ids[tid];
  __syncthreads();

  const int myc = s_cat[lane];
  int t_id = (int)blockIdx.x;
  int c = 0, base = 0, cc = 0;
  unsigned long long mask = 0ULL;
  for (c = 0; c < NCAT; ++c) {
    mask = __ballot(myc == c);
    cc = __popcll(mask);
    int sz = cc * TILES_PER_BATCH;
    if (t_id < base + sz) break;
    base += sz;
  }
  if (c >= NCAT) return;
  const int idx    = t_id - base;
  const int per_nt = cc * MT;
  const int nt     = idx / per_nt;
  const int r      = idx % per_nt;
  const int want   = r >> 1;
  const int mt     = r & 1;
  unsigned long long mm = mask;
  for (int i = 0; i < want; ++i) mm &= (mm - 1);
  const int batch = __ffsll((long long)mm) - 1;
  const int cat   = c;

  const int m0 = mt * BM;
  const int n0 = nt * BN;

  const size_t x_base = ((size_t)batch * SEQ + m0) * KDIM;
  const size_t w_base = (size_t)cat * KDIM * NDIM + n0;

  f32x4 acc[4][4] = {};
  const int wr = (wid >> 1) * 64;
  const int wc = (wid & 1) * 64;

  for (int kt = 0; kt < KDIM / BK; ++kt) {
    const int k0 = kt * BK;
    f32x4 av[4][2];
#pragma unroll
    for (int s = 0; s < 4; ++s) {
      int seg  = tid + s * 256;
      int arow = seg >> 3;
      int ak   = (seg & 7) << 3;
      const float* gp = x + x_base + (size_t)arow * KDIM + (size_t)(k0 + ak);
      av[s][0] = *(const f32x4*)gp;
      av[s][1] = *(const f32x4*)(gp + 4);
    }
    f32x4 bv[2][4];
#pragma unroll
    for (int s = 0; s < 2; ++s) {
      int u  = tid + s * 256;
      int nq = u & 31;
      int kq = u >> 5;
      const float* gp = W + w_base + (size_t)(k0 + kq * 4) * NDIM + (size_t)(nq * 4);
#pragma unroll
      for (int rr = 0; rr < 4; ++rr)
        bv[s][rr] = *(const f32x4*)(gp + (size_t)rr * NDIM);
    }
    __syncthreads();
#pragma unroll
    for (int s = 0; s < 4; ++s) {
      int seg  = tid + s * 256;
      int arow = seg >> 3;
      int akb  = (seg & 7) << 4;
      unsigned byte = (unsigned)(arow * (BK * 2)) + ((unsigned)akb ^ (((unsigned)arow & 7u) << 4));
      u32x4 q;
      q[0] = pack2(av[s][0][0], av[s][0][1]);
      q[1] = pack2(av[s][0][2], av[s][0][3]);
      q[2] = pack2(av[s][1][0], av[s][1][1]);
      q[3] = pack2(av[s][1][2], av[s][1][3]);
      *(u32x4*)(sA + byte) = q;
    }
#pragma unroll
    for (int s = 0; s < 2; ++s) {
      int u  = tid + s * 256;
      int nq = u & 31;
      int kq = u >> 5;
      unsigned swz = ((unsigned)nq & 7u) << 4;
#pragma unroll
      for (int i = 0; i < 4; ++i) {
        int n = nq * 4 + i;
        unsigned byte = (unsigned)(n * (BK * 2)) + (((unsigned)(kq * 8)) ^ swz);
        u32x2 d;
        d[0] = pack2(bv[s][0][i], bv[s][1][i]);
        d[1] = pack2(bv[s][2][i], bv[s][3][i]);
        *(u32x2*)(sB + byte) = d;
      }
    }
    __syncthreads();
#pragma unroll
    for (int kk = 0; kk < 2; ++kk) {
      const int kb = kk * 64 + ((lane >> 4) << 4);
      bf16x8 af[4], bfr[4];
#pragma unroll
      for (int mi = 0; mi < 4; ++mi) {
        int row = wr + mi * 16 + (lane & 15);
        unsigned byte = (unsigned)(row * (BK * 2)) + ((unsigned)kb ^ (((unsigned)row & 7u) << 4));
        af[mi] = *(const bf16x8*)(sA + byte);
      }
#pragma unroll
      for (int ni = 0; ni < 4; ++ni) {
        int n = wc + ni * 16 + (lane & 15);
        unsigned byte = (unsigned)(n * (BK * 2)) + ((unsigned)kb ^ ((((unsigned)n >> 2) & 7u) << 4));
        bfr[ni] = *(const bf16x8*)(sB + byte);
      }
#pragma unroll
      for (int mi = 0; mi < 4; ++mi)
#pragma unroll
        for (int ni = 0; ni < 4; ++ni)
          acc[mi][ni] = __builtin_amdgcn_mfma_f32_16x16x32_bf16(af[mi], bfr[ni], acc[mi][ni], 0, 0, 0);
    }
  }

  const int col_l = lane & 15;
  const int row_l = (lane >> 4) * 4;
#pragma unroll
  for (int mi = 0; mi < 4; ++mi) {
#pragma unroll
    for (int ni = 0; ni < 4; ++ni) {
      int gr = m0 + wr + mi * 16 + row_l;
      int gc = n0 + wc + ni * 16 + col_l;
      float bvl = bias[(size_t)cat * NDIM + gc];
      f32x4 v = acc[mi][ni];
      size_t o = ((size_t)batch * SEQ + gr) * NDIM + gc;
      out[o]            = v[0] + bvl;
      out[o + NDIM]     = v[1] + bvl;
      out[o + 2 * NDIM] = v[2] + bvl;
      out[o + 3 * NDIM] = v[3] + bvl;
    }
  }
}

extern "C" void kernel_launch(void* const* d_in, const int* in_sizes, int n_in,
                              void* d_out, int out_size, void* d_ws, size_t ws_size,
                              hipStream_t stream) {
  const float* x       = (const float*)d_in[0];
  const int*   cat_ids = (const int*)d_in[1];
  const float* W       = (const float*)d_in[2];
  const float* bias    = (const float*)d_in[3];
  float*       out     = (float*)d_out;
  (void)in_sizes; (void)n_in; (void)out_size;

  const size_t wt_bytes = (size_t)NCAT * NDIM * KDIM * 2;   // 128 MB tiled bf16 W
  const size_t xb_bytes = (size_t)BATCH * SEQ * KDIM * 2;   // 32 MB tiled bf16 x
  const size_t need = wt_bytes + xb_bytes;

  if (ws_size >= need) {
    unsigned char* Wt   = (unsigned char*)d_ws;
    unsigned char* xb_t = Wt + wt_bytes;
    hipLaunchKernelGGL(cvt_fused, dim3(CVT_W_BLOCKS + CVT_X_BLOCKS), dim3(256), 0, stream,
                       x, W, xb_t, Wt);
    hipLaunchKernelGGL(csl_gemm, dim3(G_NBLOCKS), dim3(256), 0, stream,
                       xb_t, Wt, cat_ids, bias, out);
  } else {
    hipLaunchKernelGGL(csl_fallback, dim3(NBLOCKS), dim3(256), 0, stream,
                       x, cat_ids, W, bias, out);
  }
}